// Round 4
// baseline (489.879 us; speedup 1.0000x reference)
//
#include <hip/hip_runtime.h>

#define NUM_RELS 19
#define NPB 256        // nodes per bucket (power of 2)
#define NPB_SHIFT 8
#define MAXB 400       // max buckets (N <= 102400)
#define NBLK 512       // partition chunk-blocks (2 blocks/CU)

typedef _Float16 half8 __attribute__((ext_vector_type(8)));
typedef float floatx4 __attribute__((ext_vector_type(4)));

// record pack: dstlocal(8b)<<22 | src(17b)<<5 | etype(5b)   (rec < 2^30)
// recs2 = rec & 0x3FFFFF  ->  src<<5 | etype

// ---------------- W2 -> f16 B-fragment swizzle + bcnt zero ----------------

__global__ void w2swz_kernel(const float* __restrict__ W2, _Float16* __restrict__ W2F,
                             int* __restrict__ bcnt, int B) {
    int idx = blockIdx.x * blockDim.x + threadIdx.x;
    if (idx < B) bcnt[idx] = 0;
    if (idx >= NUM_RELS * 2 * 64 * 8) return;
    int j = idx & 7, lane = (idx >> 3) & 63, nt = (idx >> 9) & 1, r = idx >> 10;
    int k = (lane >> 4) * 8 + j, n = nt * 16 + (lane & 15);
    W2F[idx] = (_Float16)W2[r * 1024 + k * 32 + n];
}

// ---------------- pass A: per-block bucket histogram ----------------

__global__ __launch_bounds__(512) void count_kernel(const int* __restrict__ dst,
                                                    int* __restrict__ blkhist,
                                                    int* __restrict__ bcnt,
                                                    int E, int B, int chunk) {
    __shared__ int h[MAXB];
    for (int i = threadIdx.x; i < B; i += 512) h[i] = 0;
    __syncthreads();
    int e0 = blockIdx.x * chunk, e1 = min(E, e0 + chunk);
    for (int e = e0 + (int)threadIdx.x; e < e1; e += 512)
        atomicAdd(&h[dst[e] >> NPB_SHIFT], 1);
    __syncthreads();
    for (int i = threadIdx.x; i < B; i += 512) {
        blkhist[blockIdx.x * B + i] = h[i];
        if (h[i]) atomicAdd(&bcnt[i], h[i]);
    }
}

// ---------------- offsets: pbase + per-bucket scan across chunk-blocks ----------------

__global__ __launch_bounds__(NBLK) void offscan_kernel(const int* __restrict__ blkhist,
                                                       const int* __restrict__ bcnt,
                                                       int* __restrict__ pbase,
                                                       int* __restrict__ offs, int B) {
    __shared__ int lds[NBLK];
    __shared__ int pbs;
    int bucket = blockIdx.x;
    int t = threadIdx.x;

    int c = (t < B) ? ((bcnt[t] + 7) & ~7) : 0;
    lds[t] = c;
    __syncthreads();
    for (int off = 1; off < NBLK; off <<= 1) {
        int x = (t >= off) ? lds[t - off] : 0;
        __syncthreads();
        lds[t] += x;
        __syncthreads();
    }
    if (t == bucket) {
        pbs = lds[t] - c;
        pbase[bucket] = pbs;
    }
    __syncthreads();
    int myp = pbs;

    int v = blkhist[t * B + bucket];
    lds[t] = v;
    __syncthreads();
    for (int off = 1; off < NBLK; off <<= 1) {
        int x = (t >= off) ? lds[t - off] : 0;
        __syncthreads();
        lds[t] += x;
        __syncthreads();
    }
    offs[t * B + bucket] = myp + lds[t] - v;
}

// ---------------- pass B: scatter 4B packed records ----------------

__global__ __launch_bounds__(512) void scatter2_kernel(
    const int* __restrict__ src, const int* __restrict__ dst, const int* __restrict__ etype,
    const int* __restrict__ offs, unsigned* __restrict__ recs4, int E, int B, int chunk) {
    __shared__ int cur[MAXB];
    for (int i = threadIdx.x; i < B; i += 512) cur[i] = offs[blockIdx.x * B + i];
    __syncthreads();
    int e0 = blockIdx.x * chunk, e1 = min(E, e0 + chunk);
    for (int e = e0 + (int)threadIdx.x; e < e1; e += 512) {
        int d = dst[e];
        int b = d >> NPB_SHIFT;
        int pos = atomicAdd(&cur[b], 1);
        recs4[pos] = ((unsigned)(d & (NPB - 1)) << 22) | ((unsigned)src[e] << 5) | (unsigned)etype[e];
    }
}

// ---------------- bucket sort (etype-sub-sorted) + layer1 -> h1 global ----------------

__global__ __launch_bounds__(512) void bsort_l1_kernel(
    const unsigned* __restrict__ recs4, const int* __restrict__ pbase, const int* __restrict__ bcnt,
    int* __restrict__ recs2, int* __restrict__ row_start, int* __restrict__ rend,
    const float* __restrict__ W1, const float* __restrict__ b1,
    _Float16* __restrict__ h1, int N) {
    __shared__ int hist[NPB];
    __shared__ int offsl[NPB];
    __shared__ int cnt2[NPB * NUM_RELS];     // counts, then reused as scatter cursors
    __shared__ float W1s[NUM_RELS * 32];
    __shared__ float b1s[32];
    int b = blockIdx.x;
    int p0 = pbase[b], n = bcnt[b];
    int t = threadIdx.x;

    if (t < NPB) hist[t] = 0;
    for (int i = t; i < NPB * NUM_RELS; i += 512) cnt2[i] = 0;
    for (int i = t; i < NUM_RELS * 32; i += 512) W1s[i] = W1[i];
    if (t < 32) b1s[t] = b1[t];
    __syncthreads();

    for (int i = t; i < n; i += 512) {
        unsigned rec = recs4[p0 + i];
        int ln = rec >> 22;
        atomicAdd(&hist[ln], 1);
        atomicAdd(&cnt2[ln * NUM_RELS + (rec & 31)], 1);
    }
    __syncthreads();
    int c = 0;
    if (t < NPB) {
        c = hist[t];
        offsl[t] = c;
    }
    __syncthreads();
    for (int off = 1; off < NPB; off <<= 1) {
        int x = 0;
        if (t < NPB && t >= off) x = offsl[t - off];
        __syncthreads();
        if (t < NPB) offsl[t] += x;
        __syncthreads();
    }
    int v0n = b << NPB_SHIFT;
    if (t < NPB) {
        int start = p0 + offsl[t] - c;  // exclusive
        int v = v0n + t;
        if (v < N) {
            row_start[v] = start;
            rend[v] = start + c;
        }
    }
    __syncthreads();

    // layer 1 from per-(node,etype) counts (h = ones -> agg is just counts)
    int o = t & 31, hw = t >> 5;  // 16 half-waves
    for (int k = hw; k < NPB; k += 16) {
        int vv = v0n + k;
        if (vv < N) {
            float acc = b1s[o];
            const int* cp = &cnt2[k * NUM_RELS];
#pragma unroll
            for (int r = 0; r < NUM_RELS; ++r) acc += (float)cp[r] * W1s[r * 32 + o];
            h1[(size_t)vv * 32 + o] = (_Float16)fmaxf(acc, 0.f);
        }
    }
    __syncthreads();  // all cnt2 count-reads complete before cursor overwrite

    // cnt2 -> per-(node,etype) exclusive offsets (node-major, etype-minor)
    if (t < NPB) {
        int base = p0 + offsl[t] - c;
        for (int r = 0; r < NUM_RELS; ++r) {
            int cv = cnt2[t * NUM_RELS + r];
            cnt2[t * NUM_RELS + r] = base;
            base += cv;
        }
    }
    __syncthreads();

    for (int i = t; i < n; i += 512) {
        unsigned rec = recs4[p0 + i];  // L2-hot
        int p = atomicAdd(&cnt2[(rec >> 22) * NUM_RELS + (rec & 31)], 1);
        recs2[p] = (int)(rec & 0x3FFFFFu);  // src<<5 | etype
    }
}

// ---------------- Edge aggregation + W2 MFMA + layer 3, fused ----------------
// Per block: 16 nodes, one half-wave each. Per-edge aggregation uses ds_add_f32
// (atomicAdd on LDS, result unused -> fire-and-forget, NO loop-carried register
// dependency). Iterations are independent -> compiler pipelines; manual 4-unroll
// keeps 4 h1 gathers in flight (round-0's proven latency-hiding shape).
// One lane owns each (node,channel) address and its atomics execute in program
// order -> bitwise identical to sequential RMW.

#define AGG_STRIDE (NUM_RELS * 32 + 4)   // 612 floats; +4 keeps MFMA ds_read_b128 ~2-way

__global__ __launch_bounds__(512) void edge23_kernel(
    const _Float16* __restrict__ h1, const int* __restrict__ row_start,
    const int* __restrict__ rend, const int* __restrict__ recs2,
    const _Float16* __restrict__ W2F,
    const float* __restrict__ b2, const float* __restrict__ W3, const float* __restrict__ b3,
    float* __restrict__ out, int N) {
    __shared__ float agg[16 * AGG_STRIDE];   // 39.2KB
    __shared__ float h2t[16 * 32];
    __shared__ float W3s[1024];
    __shared__ float b2s[32], b3s[32];
    int t = threadIdx.x;
    for (int i = t; i < 16 * AGG_STRIDE; i += 512) agg[i] = 0.f;
    for (int i = t; i < 1024; i += 512) W3s[i] = W3[i];
    if (t < 32) {
        b2s[t] = b2[t];
        b3s[t] = b3[t];
    }
    __syncthreads();

    int o = t & 31;
    int hw = t >> 5;                    // 16 half-waves = 16 nodes
    int node = blockIdx.x * 16 + hw;
    if (node < N) {
        int start = row_start[node], end = rend[node];
        float* aggn = agg + hw * AGG_STRIDE + o;
        for (int base = start; base < end; base += 32) {
            int idx = base + o;
            int m_l = (idx < end) ? recs2[idx] : 0;
            int cnt = min(32, end - base);
            int j = 0;
            for (; j + 4 <= cnt; j += 4) {
                int m0 = __shfl(m_l, j, 32);
                int m1 = __shfl(m_l, j + 1, 32);
                int m2 = __shfl(m_l, j + 2, 32);
                int m3 = __shfl(m_l, j + 3, 32);
                float v0 = (float)h1[(size_t)(m0 >> 5) * 32 + o];
                float v1 = (float)h1[(size_t)(m1 >> 5) * 32 + o];
                float v2 = (float)h1[(size_t)(m2 >> 5) * 32 + o];
                float v3 = (float)h1[(size_t)(m3 >> 5) * 32 + o];
                atomicAdd(&aggn[(m0 & 31) * 32], v0);
                atomicAdd(&aggn[(m1 & 31) * 32], v1);
                atomicAdd(&aggn[(m2 & 31) * 32], v2);
                atomicAdd(&aggn[(m3 & 31) * 32], v3);
            }
            for (; j < cnt; ++j) {
                int m = __shfl(m_l, j, 32);
                float v = (float)h1[(size_t)(m >> 5) * 32 + o];
                atomicAdd(&aggn[(m & 31) * 32], v);
            }
        }
    }
    __syncthreads();

    // MFMA: waves 0/1 handle output halves nt=0/1; C accumulates over relations
    int lane = t & 63;
    int wv = t >> 6;
    if (wv < 2) {
        int nt = wv;
        floatx4 accd = {0.f, 0.f, 0.f, 0.f};
        const float* ap0 = agg + (lane & 15) * AGG_STRIDE + (lane >> 4) * 8;
        for (int r = 0; r < NUM_RELS; ++r) {
            const float* ap = ap0 + r * 32;
            half8 a;
#pragma unroll
            for (int j = 0; j < 8; ++j) a[j] = (_Float16)ap[j];
            half8 bfrag = *(const half8*)(W2F + ((r * 2 + nt) * 64 + lane) * 8);
            accd = __builtin_amdgcn_mfma_f32_16x16x32_f16(a, bfrag, accd, 0, 0, 0);
        }
        int col = lane & 15, rowb = (lane >> 4) * 4;
#pragma unroll
        for (int reg = 0; reg < 4; ++reg) {
            h2t[(rowb + reg) * 32 + nt * 16 + col] = fmaxf(accd[reg] + b2s[nt * 16 + col], 0.f);
        }
    }
    __syncthreads();

    if (node < N) {
        float h2v = h2t[hw * 32 + o];
        float acc3 = b3s[o];
#pragma unroll
        for (int i = 0; i < 32; ++i) {
            float hi = __shfl(h2v, i, 32);
            acc3 = fmaf(hi, W3s[i * 32 + o], acc3);
        }
        out[(size_t)node * 32 + o] = acc3;
    }
}

// ---------------- Host launcher ----------------

extern "C" void kernel_launch(void* const* d_in, const int* in_sizes, int n_in,
                              void* d_out, int out_size, void* d_ws, size_t ws_size,
                              hipStream_t stream) {
    const int* src   = (const int*)d_in[0];
    const int* dst   = (const int*)d_in[1];
    const int* etype = (const int*)d_in[2];
    const float* W1  = (const float*)d_in[4];
    const float* b1  = (const float*)d_in[5];
    const float* W2  = (const float*)d_in[6];
    const float* b2  = (const float*)d_in[7];
    const float* W3  = (const float*)d_in[8];
    const float* b3  = (const float*)d_in[9];
    float* out = (float*)d_out;

    int E = in_sizes[0];
    int N = out_size / 32;
    int B = (N + NPB - 1) >> NPB_SHIFT;  // 391 for N=100000

    char* ws = (char*)d_ws;
    size_t off = 0;
    auto alloc = [&](size_t bytes) {
        void* p = ws + off;
        off = (off + bytes + 255) & ~(size_t)255;
        return p;
    };
    int* bcnt       = (int*)alloc((size_t)MAXB * 4);
    int* pbase      = (int*)alloc((size_t)MAXB * 4);
    int* blkhist    = (int*)alloc((size_t)NBLK * MAXB * 4);
    int* offs       = (int*)alloc((size_t)NBLK * MAXB * 4);
    int* row_start  = (int*)alloc((size_t)N * 4);
    int* rend       = (int*)alloc((size_t)N * 4);
    unsigned* recs4 = (unsigned*)alloc(((size_t)E + 8 * MAXB + 64) * 4);
    int* recs2      = (int*)alloc(((size_t)E + 8 * MAXB + 64) * 4);
    _Float16* h1    = (_Float16*)alloc(((size_t)N + NPB) * 32 * 2);
    _Float16* W2F   = (_Float16*)alloc((size_t)NUM_RELS * 2 * 64 * 8 * 2);

    w2swz_kernel<<<(NUM_RELS * 2 * 64 * 8 + 255) / 256, 256, 0, stream>>>(W2, W2F, bcnt, B);

    int chunk = (E + NBLK - 1) / NBLK;
    count_kernel<<<NBLK, 512, 0, stream>>>(dst, blkhist, bcnt, E, B, chunk);
    offscan_kernel<<<B, NBLK, 0, stream>>>(blkhist, bcnt, pbase, offs, B);
    scatter2_kernel<<<NBLK, 512, 0, stream>>>(src, dst, etype, offs, recs4, E, B, chunk);

    bsort_l1_kernel<<<B, 512, 0, stream>>>(recs4, pbase, bcnt, recs2, row_start, rend,
                                           W1, b1, h1, N);

    edge23_kernel<<<(N + 15) / 16, 512, 0, stream>>>(h1, row_start, rend, recs2, W2F,
                                                     b2, W3, b3, out, N);
}

// Round 5
// 485.927 us; speedup vs baseline: 1.0081x; 1.0081x over previous
//
#include <hip/hip_runtime.h>

#define NUM_RELS 19
#define NPB 256        // nodes per bucket (power of 2)
#define NPB_SHIFT 8
#define MAXB 400       // max buckets (N <= 102400)
#define NBLK 512       // partition chunk-blocks (2 blocks/CU)

typedef _Float16 half8 __attribute__((ext_vector_type(8)));
typedef float floatx4 __attribute__((ext_vector_type(4)));

// record pack: dstlocal(8b)<<22 | src(17b)<<5 | etype(5b)   (rec < 2^30)
// recs2 = rec & 0x3FFFFF  ->  src<<5 | etype

// ---------------- W2 -> f16 B-fragment swizzle + bcnt zero ----------------

__global__ void w2swz_kernel(const float* __restrict__ W2, _Float16* __restrict__ W2F,
                             int* __restrict__ bcnt, int B) {
    int idx = blockIdx.x * blockDim.x + threadIdx.x;
    if (idx < B) bcnt[idx] = 0;
    if (idx >= NUM_RELS * 2 * 64 * 8) return;
    int j = idx & 7, lane = (idx >> 3) & 63, nt = (idx >> 9) & 1, r = idx >> 10;
    int k = (lane >> 4) * 8 + j, n = nt * 16 + (lane & 15);
    W2F[idx] = (_Float16)W2[r * 1024 + k * 32 + n];
}

// ---------------- pass A: per-block bucket histogram ----------------

__global__ __launch_bounds__(512) void count_kernel(const int* __restrict__ dst,
                                                    int* __restrict__ blkhist,
                                                    int* __restrict__ bcnt,
                                                    int E, int B, int chunk) {
    __shared__ int h[MAXB];
    for (int i = threadIdx.x; i < B; i += 512) h[i] = 0;
    __syncthreads();
    int e0 = blockIdx.x * chunk, e1 = min(E, e0 + chunk);
    for (int e = e0 + (int)threadIdx.x; e < e1; e += 512)
        atomicAdd(&h[dst[e] >> NPB_SHIFT], 1);
    __syncthreads();
    for (int i = threadIdx.x; i < B; i += 512) {
        blkhist[blockIdx.x * B + i] = h[i];
        if (h[i]) atomicAdd(&bcnt[i], h[i]);
    }
}

// ---------------- offsets: pbase + per-bucket scan across chunk-blocks ----------------

__global__ __launch_bounds__(NBLK) void offscan_kernel(const int* __restrict__ blkhist,
                                                       const int* __restrict__ bcnt,
                                                       int* __restrict__ pbase,
                                                       int* __restrict__ offs, int B) {
    __shared__ int lds[NBLK];
    __shared__ int pbs;
    int bucket = blockIdx.x;
    int t = threadIdx.x;

    int c = (t < B) ? ((bcnt[t] + 7) & ~7) : 0;
    lds[t] = c;
    __syncthreads();
    for (int off = 1; off < NBLK; off <<= 1) {
        int x = (t >= off) ? lds[t - off] : 0;
        __syncthreads();
        lds[t] += x;
        __syncthreads();
    }
    if (t == bucket) {
        pbs = lds[t] - c;
        pbase[bucket] = pbs;
    }
    __syncthreads();
    int myp = pbs;

    int v = blkhist[t * B + bucket];
    lds[t] = v;
    __syncthreads();
    for (int off = 1; off < NBLK; off <<= 1) {
        int x = (t >= off) ? lds[t - off] : 0;
        __syncthreads();
        lds[t] += x;
        __syncthreads();
    }
    offs[t * B + bucket] = myp + lds[t] - v;
}

// ---------------- pass B: scatter 4B packed records ----------------

__global__ __launch_bounds__(512) void scatter2_kernel(
    const int* __restrict__ src, const int* __restrict__ dst, const int* __restrict__ etype,
    const int* __restrict__ offs, unsigned* __restrict__ recs4, int E, int B, int chunk) {
    __shared__ int cur[MAXB];
    for (int i = threadIdx.x; i < B; i += 512) cur[i] = offs[blockIdx.x * B + i];
    __syncthreads();
    int e0 = blockIdx.x * chunk, e1 = min(E, e0 + chunk);
    for (int e = e0 + (int)threadIdx.x; e < e1; e += 512) {
        int d = dst[e];
        int b = d >> NPB_SHIFT;
        int pos = atomicAdd(&cur[b], 1);
        recs4[pos] = ((unsigned)(d & (NPB - 1)) << 22) | ((unsigned)src[e] << 5) | (unsigned)etype[e];
    }
}

// ---------------- bucket sort (etype-sub-sorted) + layer1 -> h1 global ----------------

__global__ __launch_bounds__(512) void bsort_l1_kernel(
    const unsigned* __restrict__ recs4, const int* __restrict__ pbase, const int* __restrict__ bcnt,
    int* __restrict__ recs2, int* __restrict__ row_start, int* __restrict__ rend,
    const float* __restrict__ W1, const float* __restrict__ b1,
    _Float16* __restrict__ h1, int N) {
    __shared__ int hist[NPB];
    __shared__ int offsl[NPB];
    __shared__ int cnt2[NPB * NUM_RELS];     // counts, then reused as scatter cursors
    __shared__ float W1s[NUM_RELS * 32];
    __shared__ float b1s[32];
    int b = blockIdx.x;
    int p0 = pbase[b], n = bcnt[b];
    int t = threadIdx.x;

    if (t < NPB) hist[t] = 0;
    for (int i = t; i < NPB * NUM_RELS; i += 512) cnt2[i] = 0;
    for (int i = t; i < NUM_RELS * 32; i += 512) W1s[i] = W1[i];
    if (t < 32) b1s[t] = b1[t];
    __syncthreads();

    for (int i = t; i < n; i += 512) {
        unsigned rec = recs4[p0 + i];
        int ln = rec >> 22;
        atomicAdd(&hist[ln], 1);
        atomicAdd(&cnt2[ln * NUM_RELS + (rec & 31)], 1);
    }
    __syncthreads();
    int c = 0;
    if (t < NPB) {
        c = hist[t];
        offsl[t] = c;
    }
    __syncthreads();
    for (int off = 1; off < NPB; off <<= 1) {
        int x = 0;
        if (t < NPB && t >= off) x = offsl[t - off];
        __syncthreads();
        if (t < NPB) offsl[t] += x;
        __syncthreads();
    }
    int v0n = b << NPB_SHIFT;
    if (t < NPB) {
        int start = p0 + offsl[t] - c;  // exclusive
        int v = v0n + t;
        if (v < N) {
            row_start[v] = start;
            rend[v] = start + c;
        }
    }
    __syncthreads();

    // layer 1 from per-(node,etype) counts (h = ones -> agg is just counts)
    int o = t & 31, hw = t >> 5;  // 16 half-waves
    for (int k = hw; k < NPB; k += 16) {
        int vv = v0n + k;
        if (vv < N) {
            float acc = b1s[o];
            const int* cp = &cnt2[k * NUM_RELS];
#pragma unroll
            for (int r = 0; r < NUM_RELS; ++r) acc += (float)cp[r] * W1s[r * 32 + o];
            h1[(size_t)vv * 32 + o] = (_Float16)fmaxf(acc, 0.f);
        }
    }
    __syncthreads();  // all cnt2 count-reads complete before cursor overwrite

    // cnt2 -> per-(node,etype) exclusive offsets (node-major, etype-minor)
    if (t < NPB) {
        int base = p0 + offsl[t] - c;
        for (int r = 0; r < NUM_RELS; ++r) {
            int cv = cnt2[t * NUM_RELS + r];
            cnt2[t * NUM_RELS + r] = base;
            base += cv;
        }
    }
    __syncthreads();

    for (int i = t; i < n; i += 512) {
        unsigned rec = recs4[p0 + i];  // L2-hot
        int p = atomicAdd(&cnt2[(rec >> 22) * NUM_RELS + (rec & 31)], 1);
        recs2[p] = (int)(rec & 0x3FFFFFu);  // src<<5 | etype
    }
}

// ---------------- Edge aggregation + W2 MFMA + layer 3, fused ----------------
// Per block: 16 nodes, one half-wave each. Per-edge aggregation uses
// unsafeAtomicAdd on LDS -> native ds_add_f32 (fire-and-forget, no CAS loop,
// no loop-carried register dependency). Round 4 proved plain atomicAdd(float*)
// CAS-loops on LDS (360us, VALUBusy 8.6%); this is the documented native path.
// One lane owns each (node,channel) address and its atomics execute in program
// order -> bitwise identical to sequential RMW.

#define AGG_STRIDE (NUM_RELS * 32 + 4)   // 612 floats; +4 keeps MFMA ds_read_b128 ~2-way

__global__ __launch_bounds__(512) void edge23_kernel(
    const _Float16* __restrict__ h1, const int* __restrict__ row_start,
    const int* __restrict__ rend, const int* __restrict__ recs2,
    const _Float16* __restrict__ W2F,
    const float* __restrict__ b2, const float* __restrict__ W3, const float* __restrict__ b3,
    float* __restrict__ out, int N) {
    __shared__ float agg[16 * AGG_STRIDE];   // 39.2KB
    __shared__ float h2t[16 * 32];
    __shared__ float W3s[1024];
    __shared__ float b2s[32], b3s[32];
    int t = threadIdx.x;
    for (int i = t; i < 16 * AGG_STRIDE; i += 512) agg[i] = 0.f;
    for (int i = t; i < 1024; i += 512) W3s[i] = W3[i];
    if (t < 32) {
        b2s[t] = b2[t];
        b3s[t] = b3[t];
    }
    __syncthreads();

    int o = t & 31;
    int hw = t >> 5;                    // 16 half-waves = 16 nodes
    int node = blockIdx.x * 16 + hw;
    if (node < N) {
        int start = row_start[node], end = rend[node];
        float* aggn = agg + hw * AGG_STRIDE + o;
        for (int base = start; base < end; base += 32) {
            int idx = base + o;
            int m_l = (idx < end) ? recs2[idx] : 0;
            int cnt = min(32, end - base);
            int j = 0;
            for (; j + 4 <= cnt; j += 4) {
                int m0 = __shfl(m_l, j, 32);
                int m1 = __shfl(m_l, j + 1, 32);
                int m2 = __shfl(m_l, j + 2, 32);
                int m3 = __shfl(m_l, j + 3, 32);
                float v0 = (float)h1[(size_t)(m0 >> 5) * 32 + o];
                float v1 = (float)h1[(size_t)(m1 >> 5) * 32 + o];
                float v2 = (float)h1[(size_t)(m2 >> 5) * 32 + o];
                float v3 = (float)h1[(size_t)(m3 >> 5) * 32 + o];
                unsafeAtomicAdd(&aggn[(m0 & 31) * 32], v0);
                unsafeAtomicAdd(&aggn[(m1 & 31) * 32], v1);
                unsafeAtomicAdd(&aggn[(m2 & 31) * 32], v2);
                unsafeAtomicAdd(&aggn[(m3 & 31) * 32], v3);
            }
            for (; j < cnt; ++j) {
                int m = __shfl(m_l, j, 32);
                float v = (float)h1[(size_t)(m >> 5) * 32 + o];
                unsafeAtomicAdd(&aggn[(m & 31) * 32], v);
            }
        }
    }
    __syncthreads();

    // MFMA: waves 0/1 handle output halves nt=0/1; C accumulates over relations
    int lane = t & 63;
    int wv = t >> 6;
    if (wv < 2) {
        int nt = wv;
        floatx4 accd = {0.f, 0.f, 0.f, 0.f};
        const float* ap0 = agg + (lane & 15) * AGG_STRIDE + (lane >> 4) * 8;
        for (int r = 0; r < NUM_RELS; ++r) {
            const float* ap = ap0 + r * 32;
            half8 a;
#pragma unroll
            for (int j = 0; j < 8; ++j) a[j] = (_Float16)ap[j];
            half8 bfrag = *(const half8*)(W2F + ((r * 2 + nt) * 64 + lane) * 8);
            accd = __builtin_amdgcn_mfma_f32_16x16x32_f16(a, bfrag, accd, 0, 0, 0);
        }
        int col = lane & 15, rowb = (lane >> 4) * 4;
#pragma unroll
        for (int reg = 0; reg < 4; ++reg) {
            h2t[(rowb + reg) * 32 + nt * 16 + col] = fmaxf(accd[reg] + b2s[nt * 16 + col], 0.f);
        }
    }
    __syncthreads();

    if (node < N) {
        float h2v = h2t[hw * 32 + o];
        float acc3 = b3s[o];
#pragma unroll
        for (int i = 0; i < 32; ++i) {
            float hi = __shfl(h2v, i, 32);
            acc3 = fmaf(hi, W3s[i * 32 + o], acc3);
        }
        out[(size_t)node * 32 + o] = acc3;
    }
}

// ---------------- Host launcher ----------------

extern "C" void kernel_launch(void* const* d_in, const int* in_sizes, int n_in,
                              void* d_out, int out_size, void* d_ws, size_t ws_size,
                              hipStream_t stream) {
    const int* src   = (const int*)d_in[0];
    const int* dst   = (const int*)d_in[1];
    const int* etype = (const int*)d_in[2];
    const float* W1  = (const float*)d_in[4];
    const float* b1  = (const float*)d_in[5];
    const float* W2  = (const float*)d_in[6];
    const float* b2  = (const float*)d_in[7];
    const float* W3  = (const float*)d_in[8];
    const float* b3  = (const float*)d_in[9];
    float* out = (float*)d_out;

    int E = in_sizes[0];
    int N = out_size / 32;
    int B = (N + NPB - 1) >> NPB_SHIFT;  // 391 for N=100000

    char* ws = (char*)d_ws;
    size_t off = 0;
    auto alloc = [&](size_t bytes) {
        void* p = ws + off;
        off = (off + bytes + 255) & ~(size_t)255;
        return p;
    };
    int* bcnt       = (int*)alloc((size_t)MAXB * 4);
    int* pbase      = (int*)alloc((size_t)MAXB * 4);
    int* blkhist    = (int*)alloc((size_t)NBLK * MAXB * 4);
    int* offs       = (int*)alloc((size_t)NBLK * MAXB * 4);
    int* row_start  = (int*)alloc((size_t)N * 4);
    int* rend       = (int*)alloc((size_t)N * 4);
    unsigned* recs4 = (unsigned*)alloc(((size_t)E + 8 * MAXB + 64) * 4);
    int* recs2      = (int*)alloc(((size_t)E + 8 * MAXB + 64) * 4);
    _Float16* h1    = (_Float16*)alloc(((size_t)N + NPB) * 32 * 2);
    _Float16* W2F   = (_Float16*)alloc((size_t)NUM_RELS * 2 * 64 * 8 * 2);

    w2swz_kernel<<<(NUM_RELS * 2 * 64 * 8 + 255) / 256, 256, 0, stream>>>(W2, W2F, bcnt, B);

    int chunk = (E + NBLK - 1) / NBLK;
    count_kernel<<<NBLK, 512, 0, stream>>>(dst, blkhist, bcnt, E, B, chunk);
    offscan_kernel<<<B, NBLK, 0, stream>>>(blkhist, bcnt, pbase, offs, B);
    scatter2_kernel<<<NBLK, 512, 0, stream>>>(src, dst, etype, offs, recs4, E, B, chunk);

    bsort_l1_kernel<<<B, 512, 0, stream>>>(recs4, pbase, bcnt, recs2, row_start, rend,
                                           W1, b1, h1, N);

    edge23_kernel<<<(N + 15) / 16, 512, 0, stream>>>(h1, row_start, rend, recs2, W2F,
                                                     b2, W3, b3, out, N);
}

// Round 6
// 247.540 us; speedup vs baseline: 1.9790x; 1.9630x over previous
//
#include <hip/hip_runtime.h>

#define NUM_RELS 19
#define NPB 256        // nodes per bucket (power of 2)
#define NPB_SHIFT 8
#define MAXB 400       // max buckets (N <= 102400)
#define NBLK 512       // partition chunk-blocks (2 blocks/CU)

typedef _Float16 half8 __attribute__((ext_vector_type(8)));
typedef float floatx4 __attribute__((ext_vector_type(4)));

// record pack: dstlocal(8b)<<22 | src(17b)<<5 | etype(5b)   (rec < 2^30)
// recs2 = rec & 0x3FFFFF  ->  src<<5 | etype  (etype-sorted within each node)

// ---------------- W2 -> f16 B-fragment swizzle + bcnt zero ----------------

__global__ void w2swz_kernel(const float* __restrict__ W2, _Float16* __restrict__ W2F,
                             int* __restrict__ bcnt, int B) {
    int idx = blockIdx.x * blockDim.x + threadIdx.x;
    if (idx < B) bcnt[idx] = 0;
    if (idx >= NUM_RELS * 2 * 64 * 8) return;
    int j = idx & 7, lane = (idx >> 3) & 63, nt = (idx >> 9) & 1, r = idx >> 10;
    int k = (lane >> 4) * 8 + j, n = nt * 16 + (lane & 15);
    W2F[idx] = (_Float16)W2[r * 1024 + k * 32 + n];
}

// ---------------- pass A: per-block bucket histogram ----------------

__global__ __launch_bounds__(512) void count_kernel(const int* __restrict__ dst,
                                                    int* __restrict__ blkhist,
                                                    int* __restrict__ bcnt,
                                                    int E, int B, int chunk) {
    __shared__ int h[MAXB];
    for (int i = threadIdx.x; i < B; i += 512) h[i] = 0;
    __syncthreads();
    int e0 = blockIdx.x * chunk, e1 = min(E, e0 + chunk);
    for (int e = e0 + (int)threadIdx.x; e < e1; e += 512)
        atomicAdd(&h[dst[e] >> NPB_SHIFT], 1);
    __syncthreads();
    for (int i = threadIdx.x; i < B; i += 512) {
        blkhist[blockIdx.x * B + i] = h[i];
        if (h[i]) atomicAdd(&bcnt[i], h[i]);
    }
}

// ---------------- offsets: pbase + per-bucket scan across chunk-blocks ----------------

__global__ __launch_bounds__(NBLK) void offscan_kernel(const int* __restrict__ blkhist,
                                                       const int* __restrict__ bcnt,
                                                       int* __restrict__ pbase,
                                                       int* __restrict__ offs, int B) {
    __shared__ int lds[NBLK];
    __shared__ int pbs;
    int bucket = blockIdx.x;
    int t = threadIdx.x;

    int c = (t < B) ? ((bcnt[t] + 7) & ~7) : 0;
    lds[t] = c;
    __syncthreads();
    for (int off = 1; off < NBLK; off <<= 1) {
        int x = (t >= off) ? lds[t - off] : 0;
        __syncthreads();
        lds[t] += x;
        __syncthreads();
    }
    if (t == bucket) {
        pbs = lds[t] - c;
        pbase[bucket] = pbs;
    }
    __syncthreads();
    int myp = pbs;

    int v = blkhist[t * B + bucket];
    lds[t] = v;
    __syncthreads();
    for (int off = 1; off < NBLK; off <<= 1) {
        int x = (t >= off) ? lds[t - off] : 0;
        __syncthreads();
        lds[t] += x;
        __syncthreads();
    }
    offs[t * B + bucket] = myp + lds[t] - v;
}

// ---------------- pass B: scatter 4B packed records ----------------

__global__ __launch_bounds__(512) void scatter2_kernel(
    const int* __restrict__ src, const int* __restrict__ dst, const int* __restrict__ etype,
    const int* __restrict__ offs, unsigned* __restrict__ recs4, int E, int B, int chunk) {
    __shared__ int cur[MAXB];
    for (int i = threadIdx.x; i < B; i += 512) cur[i] = offs[blockIdx.x * B + i];
    __syncthreads();
    int e0 = blockIdx.x * chunk, e1 = min(E, e0 + chunk);
    for (int e = e0 + (int)threadIdx.x; e < e1; e += 512) {
        int d = dst[e];
        int b = d >> NPB_SHIFT;
        int pos = atomicAdd(&cur[b], 1);
        recs4[pos] = ((unsigned)(d & (NPB - 1)) << 22) | ((unsigned)src[e] << 5) | (unsigned)etype[e];
    }
}

// ---------------- bucket sort (etype-sub-sorted) + layer1 -> h1 global ----------------

__global__ __launch_bounds__(512) void bsort_l1_kernel(
    const unsigned* __restrict__ recs4, const int* __restrict__ pbase, const int* __restrict__ bcnt,
    int* __restrict__ recs2, int* __restrict__ row_start, int* __restrict__ rend,
    const float* __restrict__ W1, const float* __restrict__ b1,
    _Float16* __restrict__ h1, int N) {
    __shared__ int hist[NPB];
    __shared__ int offsl[NPB];
    __shared__ int cnt2[NPB * NUM_RELS];     // counts, then reused as scatter cursors
    __shared__ float W1s[NUM_RELS * 32];
    __shared__ float b1s[32];
    int b = blockIdx.x;
    int p0 = pbase[b], n = bcnt[b];
    int t = threadIdx.x;

    if (t < NPB) hist[t] = 0;
    for (int i = t; i < NPB * NUM_RELS; i += 512) cnt2[i] = 0;
    for (int i = t; i < NUM_RELS * 32; i += 512) W1s[i] = W1[i];
    if (t < 32) b1s[t] = b1[t];
    __syncthreads();

    for (int i = t; i < n; i += 512) {
        unsigned rec = recs4[p0 + i];
        int ln = rec >> 22;
        atomicAdd(&hist[ln], 1);
        atomicAdd(&cnt2[ln * NUM_RELS + (rec & 31)], 1);
    }
    __syncthreads();
    int c = 0;
    if (t < NPB) {
        c = hist[t];
        offsl[t] = c;
    }
    __syncthreads();
    for (int off = 1; off < NPB; off <<= 1) {
        int x = 0;
        if (t < NPB && t >= off) x = offsl[t - off];
        __syncthreads();
        if (t < NPB) offsl[t] += x;
        __syncthreads();
    }
    int v0n = b << NPB_SHIFT;
    if (t < NPB) {
        int start = p0 + offsl[t] - c;  // exclusive
        int v = v0n + t;
        if (v < N) {
            row_start[v] = start;
            rend[v] = start + c;
        }
    }
    __syncthreads();

    // layer 1 from per-(node,etype) counts (h = ones -> agg is just counts)
    int o = t & 31, hw = t >> 5;  // 16 half-waves
    for (int k = hw; k < NPB; k += 16) {
        int vv = v0n + k;
        if (vv < N) {
            float acc = b1s[o];
            const int* cp = &cnt2[k * NUM_RELS];
#pragma unroll
            for (int r = 0; r < NUM_RELS; ++r) acc += (float)cp[r] * W1s[r * 32 + o];
            h1[(size_t)vv * 32 + o] = (_Float16)fmaxf(acc, 0.f);
        }
    }
    __syncthreads();  // all cnt2 count-reads complete before cursor overwrite

    // cnt2 -> per-(node,etype) exclusive offsets (node-major, etype-minor)
    if (t < NPB) {
        int base = p0 + offsl[t] - c;
        for (int r = 0; r < NUM_RELS; ++r) {
            int cv = cnt2[t * NUM_RELS + r];
            cnt2[t * NUM_RELS + r] = base;
            base += cv;
        }
    }
    __syncthreads();

    for (int i = t; i < n; i += 512) {
        unsigned rec = recs4[p0 + i];  // L2-hot
        int p = atomicAdd(&cnt2[(rec >> 22) * NUM_RELS + (rec & 31)], 1);
        recs2[p] = (int)(rec & 0x3FFFFFu);  // src<<5 | etype
    }
}

// ---------------- Edge aggregation + W2 MFMA + layer 3, fused ----------------
// Per block: 16 nodes, one half-wave each. WRITE-THROUGH run accumulation:
// recs2 is etype-sorted per node, so r is non-decreasing. Keep the run sum in a
// REGISTER; every edge, plain ds_write it to aggn[r*32+o] (last write of a run
// wins; per-lane stores complete in program order). Run-boundary reset is a
// v_cndmask, not a branch. No LDS atomic (r4/r5: 358us, ds-atomic-bound), no
// LDS read-modify-write (r3: 164us, dep-chain-bound), no divergent branch
// (r2: 175us). Only loop-carried dep is acc (~6cy VALU); 4-unroll keeps 4 h1
// gathers in flight. Identical within-run summation order -> same absmax.

#define AGG_STRIDE (NUM_RELS * 32 + 4)   // 612 floats; +4 keeps MFMA ds_read_b128 ~2-way

__global__ __launch_bounds__(512) void edge23_kernel(
    const _Float16* __restrict__ h1, const int* __restrict__ row_start,
    const int* __restrict__ rend, const int* __restrict__ recs2,
    const _Float16* __restrict__ W2F,
    const float* __restrict__ b2, const float* __restrict__ W3, const float* __restrict__ b3,
    float* __restrict__ out, int N) {
    __shared__ float agg[16 * AGG_STRIDE];   // 39.2KB
    __shared__ float h2t[16 * 32];
    __shared__ float W3s[1024];
    __shared__ float b2s[32], b3s[32];
    int t = threadIdx.x;
    for (int i = t; i < 16 * AGG_STRIDE; i += 512) agg[i] = 0.f;
    for (int i = t; i < 1024; i += 512) W3s[i] = W3[i];
    if (t < 32) {
        b2s[t] = b2[t];
        b3s[t] = b3[t];
    }
    __syncthreads();

    int o = t & 31;
    int hw = t >> 5;                    // 16 half-waves = 16 nodes
    int node = blockIdx.x * 16 + hw;
    if (node < N) {
        int start = row_start[node], end = rend[node];
        float* aggn = agg + hw * AGG_STRIDE + o;
        float acc = 0.f;
        int prev_r = -1;
        for (int base = start; base < end; base += 32) {
            int idx = base + o;
            int m_l = (idx < end) ? recs2[idx] : 0;
            int cnt = min(32, end - base);
            int j = 0;
            for (; j + 4 <= cnt; j += 4) {
                int m0 = __shfl(m_l, j, 32);
                int m1 = __shfl(m_l, j + 1, 32);
                int m2 = __shfl(m_l, j + 2, 32);
                int m3 = __shfl(m_l, j + 3, 32);
                float v0 = (float)h1[(size_t)(m0 >> 5) * 32 + o];
                float v1 = (float)h1[(size_t)(m1 >> 5) * 32 + o];
                float v2 = (float)h1[(size_t)(m2 >> 5) * 32 + o];
                float v3 = (float)h1[(size_t)(m3 >> 5) * 32 + o];
                int r0 = m0 & 31, r1 = m1 & 31, r2 = m2 & 31, r3 = m3 & 31;
                acc = (r0 == prev_r) ? (acc + v0) : v0;
                aggn[r0 * 32] = acc;
                acc = (r1 == r0) ? (acc + v1) : v1;
                aggn[r1 * 32] = acc;
                acc = (r2 == r1) ? (acc + v2) : v2;
                aggn[r2 * 32] = acc;
                acc = (r3 == r2) ? (acc + v3) : v3;
                aggn[r3 * 32] = acc;
                prev_r = r3;
            }
            for (; j < cnt; ++j) {
                int m = __shfl(m_l, j, 32);
                int r = m & 31;
                float v = (float)h1[(size_t)(m >> 5) * 32 + o];
                acc = (r == prev_r) ? (acc + v) : v;
                aggn[r * 32] = acc;
                prev_r = r;
            }
        }
    }
    __syncthreads();

    // MFMA: waves 0/1 handle output halves nt=0/1; C accumulates over relations
    int lane = t & 63;
    int wv = t >> 6;
    if (wv < 2) {
        int nt = wv;
        floatx4 accd = {0.f, 0.f, 0.f, 0.f};
        const float* ap0 = agg + (lane & 15) * AGG_STRIDE + (lane >> 4) * 8;
        for (int r = 0; r < NUM_RELS; ++r) {
            const float* ap = ap0 + r * 32;
            half8 a;
#pragma unroll
            for (int j = 0; j < 8; ++j) a[j] = (_Float16)ap[j];
            half8 bfrag = *(const half8*)(W2F + ((r * 2 + nt) * 64 + lane) * 8);
            accd = __builtin_amdgcn_mfma_f32_16x16x32_f16(a, bfrag, accd, 0, 0, 0);
        }
        int col = lane & 15, rowb = (lane >> 4) * 4;
#pragma unroll
        for (int reg = 0; reg < 4; ++reg) {
            h2t[(rowb + reg) * 32 + nt * 16 + col] = fmaxf(accd[reg] + b2s[nt * 16 + col], 0.f);
        }
    }
    __syncthreads();

    if (node < N) {
        float h2v = h2t[hw * 32 + o];
        float acc3 = b3s[o];
#pragma unroll
        for (int i = 0; i < 32; ++i) {
            float hi = __shfl(h2v, i, 32);
            acc3 = fmaf(hi, W3s[i * 32 + o], acc3);
        }
        out[(size_t)node * 32 + o] = acc3;
    }
}

// ---------------- Host launcher ----------------

extern "C" void kernel_launch(void* const* d_in, const int* in_sizes, int n_in,
                              void* d_out, int out_size, void* d_ws, size_t ws_size,
                              hipStream_t stream) {
    const int* src   = (const int*)d_in[0];
    const int* dst   = (const int*)d_in[1];
    const int* etype = (const int*)d_in[2];
    const float* W1  = (const float*)d_in[4];
    const float* b1  = (const float*)d_in[5];
    const float* W2  = (const float*)d_in[6];
    const float* b2  = (const float*)d_in[7];
    const float* W3  = (const float*)d_in[8];
    const float* b3  = (const float*)d_in[9];
    float* out = (float*)d_out;

    int E = in_sizes[0];
    int N = out_size / 32;
    int B = (N + NPB - 1) >> NPB_SHIFT;  // 391 for N=100000

    char* ws = (char*)d_ws;
    size_t off = 0;
    auto alloc = [&](size_t bytes) {
        void* p = ws + off;
        off = (off + bytes + 255) & ~(size_t)255;
        return p;
    };
    int* bcnt       = (int*)alloc((size_t)MAXB * 4);
    int* pbase      = (int*)alloc((size_t)MAXB * 4);
    int* blkhist    = (int*)alloc((size_t)NBLK * MAXB * 4);
    int* offs       = (int*)alloc((size_t)NBLK * MAXB * 4);
    int* row_start  = (int*)alloc((size_t)N * 4);
    int* rend       = (int*)alloc((size_t)N * 4);
    unsigned* recs4 = (unsigned*)alloc(((size_t)E + 8 * MAXB + 64) * 4);
    int* recs2      = (int*)alloc(((size_t)E + 8 * MAXB + 64) * 4);
    _Float16* h1    = (_Float16*)alloc(((size_t)N + NPB) * 32 * 2);
    _Float16* W2F   = (_Float16*)alloc((size_t)NUM_RELS * 2 * 64 * 8 * 2);

    w2swz_kernel<<<(NUM_RELS * 2 * 64 * 8 + 255) / 256, 256, 0, stream>>>(W2, W2F, bcnt, B);

    int chunk = (E + NBLK - 1) / NBLK;
    count_kernel<<<NBLK, 512, 0, stream>>>(dst, blkhist, bcnt, E, B, chunk);
    offscan_kernel<<<B, NBLK, 0, stream>>>(blkhist, bcnt, pbase, offs, B);
    scatter2_kernel<<<NBLK, 512, 0, stream>>>(src, dst, etype, offs, recs4, E, B, chunk);

    bsort_l1_kernel<<<B, 512, 0, stream>>>(recs4, pbase, bcnt, recs2, row_start, rend,
                                           W1, b1, h1, N);

    edge23_kernel<<<(N + 15) / 16, 512, 0, stream>>>(h1, row_start, rend, recs2, W2F,
                                                     b2, W3, b3, out, N);
}